// Round 3
// baseline (289.833 us; speedup 1.0000x reference)
//
#include <hip/hip_runtime.h>

#define BDIM 4
#define HDIM 16
#define SDIM 4096
#define DDIM 64
#define NBH (BDIM * HDIM)

#define BH_STRIDE (DDIM * DDIM + DDIM)      // 4160 floats: [kv 64x64][kone 64]
#define CHUNK_FLOATS (NBH * BH_STRIDE)      // 266240 floats = 1,064,960 B

__device__ __forceinline__ float phi_f(float x) {
    // elu(x)+1 = x+1 (x>0) else exp(x)
    return x > 0.0f ? x + 1.0f : __expf(x);
}

// -------- Phase 1: kv[d][e] = sum_s phiK[s][d]*V[s][e]; kone[d] = sum_s phiK[s][d]
// 256 threads = 4 waves; each wave owns chunk_rows/4 consecutive s-rows.
// 8x8 register tile per lane (64 lanes cover the full 64x64 output).
// phiK staged in wave-PRIVATE LDS (in-order DS within a wave -> no fence, no
// barrier in the main loop). V streams straight from global (each row touched
// by exactly one wave). Cross-wave combine: 2-round phased LDS reduction.
// __launch_bounds__(256, 2): VGPR cap 256 -- 8x8 acc + prefetch needs ~150;
// cap 128 spills acc to scratch (round-1 failure: 300 MB scratch traffic).
template<bool ATOMIC>
__global__ __launch_bounds__(256, 2) void la_phase1(
    const float* __restrict__ K, const float* __restrict__ V,
    const float* __restrict__ mask, float* __restrict__ outp, int chunk_rows)
{
    // main loop: wave-private 16x64 staging at smem + w*1024
    // epilogue: [bufA 4160][bufB 4160] overlays the same space
    __shared__ __align__(16) float smem[8320];

    const int bh = blockIdx.y;
    const int b  = bh / HDIM;
    const int t  = threadIdx.x;
    const int w  = t >> 6;                  // wave 0..3
    const int l  = t & 63;
    const int rowq = l >> 4;                // staging: row group 0..3
    const int c4   = (l & 15) << 2;         // staging: col 0..60
    const int d0   = (l >> 3) << 3;         // compute tile: d rows (8)
    const int e0   = (l & 7) << 3;          // compute tile: e cols (8)

    float* kT = smem + w * 1024;            // wave-private phiK tile [16][64]

    const float* Kb = K + (size_t)bh * SDIM * DDIM;
    const float* Vb = V + (size_t)bh * SDIM * DDIM;
    const float* mb = mask + (size_t)b * SDIM;
    const float scale = 0.35355339059327373f;   // 64^-0.25

    const int rows_per_wave = chunk_rows >> 2;
    const int s_wave = blockIdx.x * chunk_rows + w * rows_per_wave;
    const int ntiles = rows_per_wave >> 4;

    float acc[8][8] = {};
    float k1s[4] = {0.f, 0.f, 0.f, 0.f};    // kone partial for cols c4..c4+3

    // prefetch tile 0 (4 rows x float4 per lane)
    float4 kr[4]; float mmr[4];
    #pragma unroll
    for (int j = 0; j < 4; ++j) {
        const int s = s_wave + rowq + (j << 2);
        kr[j]  = *(const float4*)(Kb + (size_t)s * DDIM + c4);
        mmr[j] = mb[s];
    }

    for (int tt = 0; tt < ntiles; ++tt) {
        // phi once per element at staging; kone folded in here
        #pragma unroll
        for (int j = 0; j < 4; ++j) {
            float4 p;
            p.x = phi_f(kr[j].x * scale) * mmr[j];
            p.y = phi_f(kr[j].y * scale) * mmr[j];
            p.z = phi_f(kr[j].z * scale) * mmr[j];
            p.w = phi_f(kr[j].w * scale) * mmr[j];
            k1s[0] += p.x; k1s[1] += p.y; k1s[2] += p.z; k1s[3] += p.w;
            *(float4*)&kT[(rowq + (j << 2)) * DDIM + c4] = p;
        }
        // prefetch next tile's K while this tile computes
        if (tt + 1 < ntiles) {
            #pragma unroll
            for (int j = 0; j < 4; ++j) {
                const int s = s_wave + ((tt + 1) << 4) + rowq + (j << 2);
                kr[j]  = *(const float4*)(Kb + (size_t)s * DDIM + c4);
                mmr[j] = mb[s];
            }
        }

        const int s_tile = s_wave + (tt << 4);
        #pragma unroll
        for (int ss = 0; ss < 16; ++ss) {
            const float4 a0 = *(const float4*)&kT[ss * DDIM + d0];
            const float4 a1 = *(const float4*)&kT[ss * DDIM + d0 + 4];
            const float4 v0 = *(const float4*)(Vb + (size_t)(s_tile + ss) * DDIM + e0);
            const float4 v1 = *(const float4*)(Vb + (size_t)(s_tile + ss) * DDIM + e0 + 4);
            const float av[8] = {a0.x, a0.y, a0.z, a0.w, a1.x, a1.y, a1.z, a1.w};
            const float vv[8] = {v0.x, v0.y, v0.z, v0.w, v1.x, v1.y, v1.z, v1.w};
            #pragma unroll
            for (int i = 0; i < 8; ++i)
                #pragma unroll
                for (int j = 0; j < 8; ++j)
                    acc[i][j] += av[i] * vv[j];   // 64 FMA per 32 B LDS
        }
    }

    // kone: sum across the 4 lanes sharing c4 (l, l^16, l^32, l^48)
    #pragma unroll
    for (int i = 0; i < 4; ++i) {
        k1s[i] += __shfl_xor(k1s[i], 16);
        k1s[i] += __shfl_xor(k1s[i], 32);
    }

    // phased cross-wave reduction: waves {0,2} -> bufA, {1,3} -> bufB
    __syncthreads();
    float* bufA = smem;
    float* bufB = smem + 4160;
    if (w < 2) {
        float* Bp = w ? bufB : bufA;
        #pragma unroll
        for (int i = 0; i < 8; ++i) {
            *(float4*)&Bp[(d0 + i) * DDIM + e0]     = make_float4(acc[i][0], acc[i][1], acc[i][2], acc[i][3]);
            *(float4*)&Bp[(d0 + i) * DDIM + e0 + 4] = make_float4(acc[i][4], acc[i][5], acc[i][6], acc[i][7]);
        }
        if (l < 16) *(float4*)&Bp[4096 + (l << 2)] = make_float4(k1s[0], k1s[1], k1s[2], k1s[3]);
    }
    __syncthreads();
    if (w >= 2) {
        float* Bp = (w == 3) ? bufB : bufA;
        #pragma unroll
        for (int i = 0; i < 8; ++i) {
            float4 x0 = *(float4*)&Bp[(d0 + i) * DDIM + e0];
            float4 x1 = *(float4*)&Bp[(d0 + i) * DDIM + e0 + 4];
            x0.x += acc[i][0]; x0.y += acc[i][1]; x0.z += acc[i][2]; x0.w += acc[i][3];
            x1.x += acc[i][4]; x1.y += acc[i][5]; x1.z += acc[i][6]; x1.w += acc[i][7];
            *(float4*)&Bp[(d0 + i) * DDIM + e0]     = x0;
            *(float4*)&Bp[(d0 + i) * DDIM + e0 + 4] = x1;
        }
        if (l < 16) {
            float4 x = *(float4*)&Bp[4096 + (l << 2)];
            x.x += k1s[0]; x.y += k1s[1]; x.z += k1s[2]; x.w += k1s[3];
            *(float4*)&Bp[4096 + (l << 2)] = x;
        }
    }
    __syncthreads();

    float* base = ATOMIC ? (outp + (size_t)bh * BH_STRIDE)
                         : (outp + ((size_t)blockIdx.x * NBH + bh) * BH_STRIDE);
    for (int g = t; g < BH_STRIDE / 4; g += 256) {
        const float4 xa = ((const float4*)bufA)[g];
        const float4 xb = ((const float4*)bufB)[g];
        if (ATOMIC) {
            atomicAdd(&base[4 * g + 0], xa.x + xb.x);
            atomicAdd(&base[4 * g + 1], xa.y + xb.y);
            atomicAdd(&base[4 * g + 2], xa.z + xb.z);
            atomicAdd(&base[4 * g + 3], xa.w + xb.w);
        } else {
            *(float4*)&base[4 * g] = make_float4(xa.x + xb.x, xa.y + xb.y, xa.z + xb.z, xa.w + xb.w);
        }
    }
}

// -------- Reduce: fin[i] = sum_c part[c][i]; compile-time NC -> all loads in flight
template<int NCT>
__global__ __launch_bounds__(256) void la_reduce(
    const float* __restrict__ part, float* __restrict__ fin)
{
    const int g = blockIdx.x * 256 + threadIdx.x;     // float4 index
    const float4* p4 = (const float4*)part;
    float4 s = p4[g];
    #pragma unroll
    for (int c = 1; c < NCT; ++c) {
        const float4 v = p4[(size_t)c * (CHUNK_FLOATS / 4) + g];
        s.x += v.x; s.y += v.y; s.z += v.z; s.w += v.w;
    }
    ((float4*)fin)[g] = s;
}

// -------- Phase 2: out[s][e] = (sum_d phiQ[s][d]*kv[d][e]) * mm / (mm*sum_d phiQ[s][d]*kone[d] + 1e-8)
// 256 threads = 4 waves, 256 q-rows per block (64 per wave), 8x8 tile per lane.
// Q goes global->registers directly; only kv (16 KB) + kone live in LDS.
// SOFTWARE PIPELINE (the round-3 fix): double-buffer the per-dt Q quad so
// iteration dt's 288-inst FMA body covers iteration dt+1's loads. Round-2 had
// loads glued to uses (VGPR=80, VALUBusy 45%, latency-bound at 92 us).
__global__ __launch_bounds__(256, 2) void la_phase2(
    const float* __restrict__ Q, const float* __restrict__ mask,
    const float* __restrict__ fin_all, float* __restrict__ out)
{
    __shared__ __align__(16) float kvL[DDIM * DDIM];   // 16 KB
    __shared__ __align__(16) float koL[DDIM];

    const int bh = blockIdx.y;
    const int b  = bh / HDIM;
    const int t  = threadIdx.x;
    const int w  = t >> 6;
    const int l  = t & 63;
    const int e0 = (l & 7) << 3;
    const int r0 = blockIdx.x * 256 + (w << 6) + ((l >> 3) << 3);

    const float* fin = fin_all + (size_t)bh * BH_STRIDE;
    {
        const float4* src = (const float4*)fin;
        float4* dst = (float4*)kvL;
        #pragma unroll
        for (int k = 0; k < 4; ++k) dst[t + 256 * k] = src[t + 256 * k];
        if (t < DDIM) koL[t] = fin[DDIM * DDIM + t];
    }

    const float* Qb = Q + (size_t)bh * SDIM * DDIM;
    const float* mb = mask + (size_t)b * SDIM;
    const float scale = 0.35355339059327373f;

    // prefetch dt=0's Q quad before the barrier (overlaps LDS staging wait)
    float4 qc[8], qn[8];
    #pragma unroll
    for (int i = 0; i < 8; ++i)
        qc[i] = *(const float4*)(Qb + (size_t)(r0 + i) * DDIM);

    __syncthreads();

    float acc[8][8] = {};
    float nrm[8] = {0.f, 0.f, 0.f, 0.f, 0.f, 0.f, 0.f, 0.f};

    #pragma unroll 1
    for (int dt = 0; dt < 16; ++dt) {       // d in quads of 4
        const int d4 = dt << 2;
        // issue next quad's loads first: they retire under this quad's FMAs
        if (dt < 15) {
            #pragma unroll
            for (int i = 0; i < 8; ++i)
                qn[i] = *(const float4*)(Qb + (size_t)(r0 + i) * DDIM + d4 + 4);
        }
        float4 qp[8];
        #pragma unroll
        for (int i = 0; i < 8; ++i) {
            qp[i].x = phi_f(qc[i].x * scale);
            qp[i].y = phi_f(qc[i].y * scale);
            qp[i].z = phi_f(qc[i].z * scale);
            qp[i].w = phi_f(qc[i].w * scale);
        }
        const float4 ko4 = *(const float4*)&koL[d4];
        #pragma unroll
        for (int dd = 0; dd < 4; ++dd) {
            const float4 b0 = *(const float4*)&kvL[(d4 + dd) * DDIM + e0];
            const float4 b1 = *(const float4*)&kvL[(d4 + dd) * DDIM + e0 + 4];
            const float bv[8] = {b0.x, b0.y, b0.z, b0.w, b1.x, b1.y, b1.z, b1.w};
            const float kod = (dd == 0) ? ko4.x : (dd == 1) ? ko4.y : (dd == 2) ? ko4.z : ko4.w;
            #pragma unroll
            for (int i = 0; i < 8; ++i) {
                const float a = (dd == 0) ? qp[i].x : (dd == 1) ? qp[i].y : (dd == 2) ? qp[i].z : qp[i].w;
                nrm[i] += a * kod;
                #pragma unroll
                for (int j = 0; j < 8; ++j)
                    acc[i][j] += a * bv[j];
            }
        }
        #pragma unroll
        for (int i = 0; i < 8; ++i) qc[i] = qn[i];
    }

    // mask folds in exactly: out = mm*A / (mm*B + 1e-8)
    float* ob = out + (size_t)bh * SDIM * DDIM;
    #pragma unroll
    for (int i = 0; i < 8; ++i) {
        const float mm  = mb[r0 + i];
        const float inv = mm / (mm * nrm[i] + 1e-8f);
        *(float4*)(ob + (size_t)(r0 + i) * DDIM + e0) =
            make_float4(acc[i][0] * inv, acc[i][1] * inv, acc[i][2] * inv, acc[i][3] * inv);
        *(float4*)(ob + (size_t)(r0 + i) * DDIM + e0 + 4) =
            make_float4(acc[i][4] * inv, acc[i][5] * inv, acc[i][6] * inv, acc[i][7] * inv);
    }
}

extern "C" void kernel_launch(void* const* d_in, const int* in_sizes, int n_in,
                              void* d_out, int out_size, void* d_ws, size_t ws_size,
                              hipStream_t stream) {
    const float* Q = (const float*)d_in[0];
    const float* K = (const float*)d_in[1];
    const float* V = (const float*)d_in[2];
    const float* M = (const float*)d_in[3];
    float* out = (float*)d_out;

    const size_t chunk_bytes = (size_t)CHUNK_FLOATS * sizeof(float);  // 1,064,960 B

    // ws_size is constant across calls -> same path every call (graph-safe)
    if (ws_size >= 33 * chunk_bytes) {          // 35.1 MB: 32 partials + final
        float* part = (float*)d_ws;
        float* fin  = part + (size_t)32 * CHUNK_FLOATS;
        la_phase1<false><<<dim3(32, NBH), dim3(256), 0, stream>>>(K, V, M, part, SDIM / 32);
        la_reduce<32><<<dim3(CHUNK_FLOATS / 4 / 256), dim3(256), 0, stream>>>(part, fin);
        la_phase2<<<dim3(SDIM / 256, NBH), dim3(256), 0, stream>>>(Q, M, fin, out);
    } else if (ws_size >= 17 * chunk_bytes) {   // 18.1 MB: 16 partials + final
        float* part = (float*)d_ws;
        float* fin  = part + (size_t)16 * CHUNK_FLOATS;
        la_phase1<false><<<dim3(16, NBH), dim3(256), 0, stream>>>(K, V, M, part, SDIM / 16);
        la_reduce<16><<<dim3(CHUNK_FLOATS / 4 / 256), dim3(256), 0, stream>>>(part, fin);
        la_phase2<<<dim3(SDIM / 256, NBH), dim3(256), 0, stream>>>(Q, M, fin, out);
    } else {
        // fallback: atomic accumulation directly into final buffer (1.06 MB)
        float* fin = (float*)d_ws;
        hipMemsetAsync(d_ws, 0, chunk_bytes, stream);
        la_phase1<true><<<dim3(16, NBH), dim3(256), 0, stream>>>(K, V, M, fin, SDIM / 16);
        la_phase2<<<dim3(SDIM / 256, NBH), dim3(256), 0, stream>>>(Q, M, fin, out);
    }
}

// Round 4
// 254.531 us; speedup vs baseline: 1.1387x; 1.1387x over previous
//
#include <hip/hip_runtime.h>

#define BDIM 4
#define HDIM 16
#define SDIM 4096
#define DDIM 64
#define NBH (BDIM * HDIM)

#define NC 16                               // s-chunks for phase1
#define BH_STRIDE (DDIM * DDIM + DDIM)      // 4160 floats: [kv 64x64][kone 64]
#define CHUNK_FLOATS (NBH * BH_STRIDE)      // 266240 floats = 1,064,960 B

__device__ __forceinline__ float phi_f(float x) {
    // elu(x)+1 = x+1 (x>0) else exp(x)
    return x > 0.0f ? x + 1.0f : __expf(x);
}

// -------- Phase 1: kv[d][e] = sum_s phiK[s][d]*V[s][e]; kone[d] = sum_s phiK[s][d]
// 256 threads = 4 waves; each wave owns chunk_rows/4 consecutive s-rows.
// 8x8 register tile per lane. phiK staged in wave-PRIVATE LDS (in-order DS
// within a wave -> no fence, no barrier in the main loop). V streams from
// global. NC=16 (round-3 lesson: NC=32 halves tiles/block -> epilogue+partial
// traffic costs ~10 us net).
template<bool ATOMIC>
__global__ __launch_bounds__(256, 2) void la_phase1(
    const float* __restrict__ K, const float* __restrict__ V,
    const float* __restrict__ mask, float* __restrict__ outp, int chunk_rows)
{
    // main loop: wave-private 16x64 staging at smem + w*1024
    // epilogue: [bufA 4160][bufB 4160] overlays the same space
    __shared__ __align__(16) float smem[8320];

    const int bh = blockIdx.y;
    const int b  = bh / HDIM;
    const int t  = threadIdx.x;
    const int w  = t >> 6;                  // wave 0..3
    const int l  = t & 63;
    const int rowq = l >> 4;                // staging: row group 0..3
    const int c4   = (l & 15) << 2;         // staging: col 0..60
    const int d0   = (l >> 3) << 3;         // compute tile: d rows (8)
    const int e0   = (l & 7) << 3;          // compute tile: e cols (8)

    float* kT = smem + w * 1024;            // wave-private phiK tile [16][64]

    const float* Kb = K + (size_t)bh * SDIM * DDIM;
    const float* Vb = V + (size_t)bh * SDIM * DDIM;
    const float* mb = mask + (size_t)b * SDIM;
    const float scale = 0.35355339059327373f;   // 64^-0.25

    const int rows_per_wave = chunk_rows >> 2;
    const int s_wave = blockIdx.x * chunk_rows + w * rows_per_wave;
    const int ntiles = rows_per_wave >> 4;

    float acc[8][8] = {};
    float k1s[4] = {0.f, 0.f, 0.f, 0.f};    // kone partial for cols c4..c4+3

    // prefetch tile 0 (4 rows x float4 per lane)
    float4 kr[4]; float mmr[4];
    #pragma unroll
    for (int j = 0; j < 4; ++j) {
        const int s = s_wave + rowq + (j << 2);
        kr[j]  = *(const float4*)(Kb + (size_t)s * DDIM + c4);
        mmr[j] = mb[s];
    }

    for (int tt = 0; tt < ntiles; ++tt) {
        #pragma unroll
        for (int j = 0; j < 4; ++j) {
            float4 p;
            p.x = phi_f(kr[j].x * scale) * mmr[j];
            p.y = phi_f(kr[j].y * scale) * mmr[j];
            p.z = phi_f(kr[j].z * scale) * mmr[j];
            p.w = phi_f(kr[j].w * scale) * mmr[j];
            k1s[0] += p.x; k1s[1] += p.y; k1s[2] += p.z; k1s[3] += p.w;
            *(float4*)&kT[(rowq + (j << 2)) * DDIM + c4] = p;
        }
        if (tt + 1 < ntiles) {
            #pragma unroll
            for (int j = 0; j < 4; ++j) {
                const int s = s_wave + ((tt + 1) << 4) + rowq + (j << 2);
                kr[j]  = *(const float4*)(Kb + (size_t)s * DDIM + c4);
                mmr[j] = mb[s];
            }
        }

        const int s_tile = s_wave + (tt << 4);
        #pragma unroll
        for (int ss = 0; ss < 16; ++ss) {
            const float4 a0 = *(const float4*)&kT[ss * DDIM + d0];
            const float4 a1 = *(const float4*)&kT[ss * DDIM + d0 + 4];
            const float4 v0 = *(const float4*)(Vb + (size_t)(s_tile + ss) * DDIM + e0);
            const float4 v1 = *(const float4*)(Vb + (size_t)(s_tile + ss) * DDIM + e0 + 4);
            const float av[8] = {a0.x, a0.y, a0.z, a0.w, a1.x, a1.y, a1.z, a1.w};
            const float vv[8] = {v0.x, v0.y, v0.z, v0.w, v1.x, v1.y, v1.z, v1.w};
            #pragma unroll
            for (int i = 0; i < 8; ++i)
                #pragma unroll
                for (int j = 0; j < 8; ++j)
                    acc[i][j] += av[i] * vv[j];   // 64 FMA per 32 B LDS
        }
    }

    // kone: sum across the 4 lanes sharing c4 (l, l^16, l^32, l^48)
    #pragma unroll
    for (int i = 0; i < 4; ++i) {
        k1s[i] += __shfl_xor(k1s[i], 16);
        k1s[i] += __shfl_xor(k1s[i], 32);
    }

    // phased cross-wave reduction: waves {0,2} -> bufA, {1,3} -> bufB
    __syncthreads();
    float* bufA = smem;
    float* bufB = smem + 4160;
    if (w < 2) {
        float* Bp = w ? bufB : bufA;
        #pragma unroll
        for (int i = 0; i < 8; ++i) {
            *(float4*)&Bp[(d0 + i) * DDIM + e0]     = make_float4(acc[i][0], acc[i][1], acc[i][2], acc[i][3]);
            *(float4*)&Bp[(d0 + i) * DDIM + e0 + 4] = make_float4(acc[i][4], acc[i][5], acc[i][6], acc[i][7]);
        }
        if (l < 16) *(float4*)&Bp[4096 + (l << 2)] = make_float4(k1s[0], k1s[1], k1s[2], k1s[3]);
    }
    __syncthreads();
    if (w >= 2) {
        float* Bp = (w == 3) ? bufB : bufA;
        #pragma unroll
        for (int i = 0; i < 8; ++i) {
            float4 x0 = *(float4*)&Bp[(d0 + i) * DDIM + e0];
            float4 x1 = *(float4*)&Bp[(d0 + i) * DDIM + e0 + 4];
            x0.x += acc[i][0]; x0.y += acc[i][1]; x0.z += acc[i][2]; x0.w += acc[i][3];
            x1.x += acc[i][4]; x1.y += acc[i][5]; x1.z += acc[i][6]; x1.w += acc[i][7];
            *(float4*)&Bp[(d0 + i) * DDIM + e0]     = x0;
            *(float4*)&Bp[(d0 + i) * DDIM + e0 + 4] = x1;
        }
        if (l < 16) {
            float4 x = *(float4*)&Bp[4096 + (l << 2)];
            x.x += k1s[0]; x.y += k1s[1]; x.z += k1s[2]; x.w += k1s[3];
            *(float4*)&Bp[4096 + (l << 2)] = x;
        }
    }
    __syncthreads();

    float* base = ATOMIC ? (outp + (size_t)bh * BH_STRIDE)
                         : (outp + ((size_t)blockIdx.x * NBH + bh) * BH_STRIDE);
    for (int g = t; g < BH_STRIDE / 4; g += 256) {
        const float4 xa = ((const float4*)bufA)[g];
        const float4 xb = ((const float4*)bufB)[g];
        if (ATOMIC) {
            atomicAdd(&base[4 * g + 0], xa.x + xb.x);
            atomicAdd(&base[4 * g + 1], xa.y + xb.y);
            atomicAdd(&base[4 * g + 2], xa.z + xb.z);
            atomicAdd(&base[4 * g + 3], xa.w + xb.w);
        } else {
            *(float4*)&base[4 * g] = make_float4(xa.x + xb.x, xa.y + xb.y, xa.z + xb.z, xa.w + xb.w);
        }
    }
}

// -------- Reduce: fin[i] = sum_c part[c][i]; compile-time NC -> all loads in flight
template<int NCT>
__global__ __launch_bounds__(256) void la_reduce(
    const float* __restrict__ part, float* __restrict__ fin)
{
    const int g = blockIdx.x * 256 + threadIdx.x;     // float4 index
    const float4* p4 = (const float4*)part;
    float4 s = p4[g];
    #pragma unroll
    for (int c = 1; c < NCT; ++c) {
        const float4 v = p4[(size_t)c * (CHUNK_FLOATS / 4) + g];
        s.x += v.x; s.y += v.y; s.z += v.z; s.w += v.w;
    }
    ((float4*)fin)[g] = s;
}

// -------- Phase 2: out[s][e] = (sum_d phiQ[s][d]*kv[d][e]) * mm / (mm*sum_d phiQ[s][d]*kone[d] + 1e-8)
// Round-4 redesign: kill the 8x redundant phi work.
// 256 threads = 4 waves; block covers 128 q-rows (wave w: rows w*32..+32).
// Lane tile 4 rows x 8 cols (g = l>>3 row-group, e0 = (l&7)*8).
// Per dt (4 d-values): lane l loads ONE distinct row (l&31), phi's it, and
// publishes the quad to wave-private LDS pqw[w] (double-buffered across dt,
// in-wave DS ordering -> no barrier). The a-operand comes back as one
// ds_read_b128 per row, broadcast across the 8 lanes sharing the group.
// Per-dt instrs drop ~480 -> ~190 (144 FMA = 76% density).
// Grid 2048 blocks (8/CU); VGPR ~96 -> 5 waves/SIMD.
__global__ __launch_bounds__(256, 4) void la_phase2(
    const float* __restrict__ Q, const float* __restrict__ mask,
    const float* __restrict__ fin_all, float* __restrict__ out)
{
    __shared__ __align__(16) float kvL[DDIM * DDIM];   // 16 KB
    __shared__ __align__(16) float koL[DDIM];
    __shared__ __align__(16) float pqw[4][2][32][4];   // 4 KB phi(Q) staging

    const int bh = blockIdx.y;
    const int b  = bh / HDIM;
    const int t  = threadIdx.x;
    const int w  = t >> 6;
    const int l  = t & 63;
    const int g  = l >> 3;                  // row group 0..7 (4 rows each)
    const int e0 = (l & 7) << 3;
    const int rbase = blockIdx.x * 128 + (w << 5);   // wave's 32 rows
    const int rown  = l & 31;               // row this lane loads (dup for l>=32)

    const float* fin = fin_all + (size_t)bh * BH_STRIDE;
    {
        const float4* src = (const float4*)fin;
        float4* dst = (float4*)kvL;
        #pragma unroll
        for (int k2 = 0; k2 < 4; ++k2) dst[t + 256 * k2] = src[t + 256 * k2];
        if (t < DDIM) koL[t] = fin[DDIM * DDIM + t];
    }

    const float* Qb   = Q + (size_t)bh * SDIM * DDIM;
    const float* mb   = mask + (size_t)b * SDIM;
    const float* Qrow = Qb + (size_t)(rbase + rown) * DDIM;
    const float scale = 0.35355339059327373f;

    // prologue loads overlap the kv-staging barrier
    float4 q0 = *(const float4*)(Qrow);      // dt=0
    float4 qn = *(const float4*)(Qrow + 4);  // dt=1
    __syncthreads();

    // stage dt=0's phi into buf 0 (wave-private; in-wave ordering suffices)
    {
        float4 p;
        p.x = phi_f(q0.x * scale);
        p.y = phi_f(q0.y * scale);
        p.z = phi_f(q0.z * scale);
        p.w = phi_f(q0.w * scale);
        if (l < 32) *(float4*)&pqw[w][0][rown][0] = p;
    }

    float acc[4][8] = {};
    float nrm[4] = {0.f, 0.f, 0.f, 0.f};

    #pragma unroll 1
    for (int dt = 0; dt < 16; ++dt) {
        const int d4  = dt << 2;
        const int cur = dt & 1;
        // stage next dt's phi into the other buffer; prefetch dt+2's Q
        if (dt < 15) {
            float4 p;
            p.x = phi_f(qn.x * scale);
            p.y = phi_f(qn.y * scale);
            p.z = phi_f(qn.z * scale);
            p.w = phi_f(qn.w * scale);
            if (l < 32) *(float4*)&pqw[w][cur ^ 1][rown][0] = p;
            if (dt < 14) qn = *(const float4*)(Qrow + ((dt + 2) << 2));
        }
        // a-rows for this dt (written by this wave at dt-1; in-order DS)
        float4 ar[4];
        #pragma unroll
        for (int i = 0; i < 4; ++i)
            ar[i] = *(const float4*)&pqw[w][cur][(g << 2) + i][0];
        const float4 ko4 = *(const float4*)&koL[d4];
        #pragma unroll
        for (int dd = 0; dd < 4; ++dd) {
            const float4 b0 = *(const float4*)&kvL[(d4 + dd) * DDIM + e0];
            const float4 b1 = *(const float4*)&kvL[(d4 + dd) * DDIM + e0 + 4];
            const float kod = (dd == 0) ? ko4.x : (dd == 1) ? ko4.y : (dd == 2) ? ko4.z : ko4.w;
            #pragma unroll
            for (int i = 0; i < 4; ++i) {
                const float a = (dd == 0) ? ar[i].x : (dd == 1) ? ar[i].y : (dd == 2) ? ar[i].z : ar[i].w;
                nrm[i] += a * kod;
                acc[i][0] += a * b0.x; acc[i][1] += a * b0.y; acc[i][2] += a * b0.z; acc[i][3] += a * b0.w;
                acc[i][4] += a * b1.x; acc[i][5] += a * b1.y; acc[i][6] += a * b1.z; acc[i][7] += a * b1.w;
            }
        }
    }

    // mask folds in exactly: out = mm*A / (mm*B + 1e-8)
    float* ob = out + (size_t)bh * SDIM * DDIM;
    #pragma unroll
    for (int i = 0; i < 4; ++i) {
        const int r  = rbase + (g << 2) + i;
        const float mm  = mb[r];
        const float inv = mm / (mm * nrm[i] + 1e-8f);
        *(float4*)(ob + (size_t)r * DDIM + e0) =
            make_float4(acc[i][0] * inv, acc[i][1] * inv, acc[i][2] * inv, acc[i][3] * inv);
        *(float4*)(ob + (size_t)r * DDIM + e0 + 4) =
            make_float4(acc[i][4] * inv, acc[i][5] * inv, acc[i][6] * inv, acc[i][7] * inv);
    }
}

extern "C" void kernel_launch(void* const* d_in, const int* in_sizes, int n_in,
                              void* d_out, int out_size, void* d_ws, size_t ws_size,
                              hipStream_t stream) {
    const float* Q = (const float*)d_in[0];
    const float* K = (const float*)d_in[1];
    const float* V = (const float*)d_in[2];
    const float* M = (const float*)d_in[3];
    float* out = (float*)d_out;

    const size_t chunk_bytes = (size_t)CHUNK_FLOATS * sizeof(float);  // 1,064,960 B

    // ws_size is constant across calls -> same path every call (graph-safe)
    if (ws_size >= (size_t)(NC + 1) * chunk_bytes) {   // 18.1 MB: 16 partials + final
        float* part = (float*)d_ws;
        float* fin  = part + (size_t)NC * CHUNK_FLOATS;
        la_phase1<false><<<dim3(NC, NBH), dim3(256), 0, stream>>>(K, V, M, part, SDIM / NC);
        la_reduce<NC><<<dim3(CHUNK_FLOATS / 4 / 256), dim3(256), 0, stream>>>(part, fin);
        la_phase2<<<dim3(SDIM / 128, NBH), dim3(256), 0, stream>>>(Q, M, fin, out);
    } else {
        // fallback: atomic accumulation directly into final buffer (1.06 MB)
        float* fin = (float*)d_ws;
        hipMemsetAsync(d_ws, 0, chunk_bytes, stream);
        la_phase1<true><<<dim3(NC, NBH), dim3(256), 0, stream>>>(K, V, M, fin, SDIM / NC);
        la_phase2<<<dim3(SDIM / 128, NBH), dim3(256), 0, stream>>>(Q, M, fin, out);
    }
}